// Round 9
// baseline (35.943 us; speedup 1.0000x reference)
//
#include <hip/hip_runtime.h>
#include <hip/hip_bf16.h>

typedef __attribute__((ext_vector_type(8))) short bf16x8;
typedef __attribute__((ext_vector_type(4))) float f32x4;

#define B_NUM 2048
#define F_NUM 40
#define E_DIM 32
#define P_NUM 780
#define D_DIM 16
#define PC_N  78            // pair chunks
#define PC_SZ 10            // 78*10 = 780 exactly
#define LN_EPS 1e-3f

// workspace layout (bytes)
#define WF_OFF 0
#define WF_BYTES (P_NUM * 2 * 64 * 8 * 2)          // 1.6 MB W fragments
#define XB_OFF  WF_BYTES
#define XB_BYTES (F_NUM * 4 * B_NUM * 8 * 2)       // 5.2 MB packed bf16 x [f][e8][b][8]
#define DW_OFF  (XB_OFF + XB_BYTES)
#define DW_BYTES (P_NUM * D_DIM * 2)               // 25 KB bf16 dense_w
#define HP_OFF  (DW_OFF + DW_BYTES)                // hpart 78*2048*16*4 = 10.2 MB

static __device__ __forceinline__ unsigned short f2b(float f) {
  unsigned u = __builtin_bit_cast(unsigned, f);
  u += 0x7fffu + ((u >> 16) & 1u);                 // round-to-nearest-even
  return (unsigned short)(u >> 16);
}
static __device__ __forceinline__ short f2bs(float f) { return (short)f2b(f); }
// compiler-friendly convert (pattern-matches to v_cvt_pk_bf16_f32 in pairs)
static __device__ __forceinline__ short fcvt(float f) {
  return (short)__bfloat16_as_ushort(__float2bfloat16(f));
}
static __device__ __forceinline__ float b2f(unsigned short u) {
  return __builtin_bit_cast(float, (unsigned)u << 16);
}

// ---------------------------------------------------------------------------
// Prep:
//  blocks [0,640): x -> packed bf16 [f][e8][b][8]. Thread = (fp, b) with b
//    minor: each thread reads one full 64 B half-row (100% line use) and
//    writes two coalesced 16 B bf16x8 planes.
//  blocks [640,835): W -> per-lane A-fragments, f-permuted rows
//    (m -> fo=(m>>2)*8+frag*4+(m&3)), via LDS transpose. One pair per wave.
//  block 835: dense_w -> bf16 table.
__global__ __launch_bounds__(256) void prep_kernel(
    const float* __restrict__ x, const float* __restrict__ W,
    const float* __restrict__ dw, short* __restrict__ xbp,
    short* __restrict__ wfrag, unsigned short* __restrict__ dwbf) {
  const int lane = threadIdx.x & 63;
  const int wv   = threadIdx.x >> 6;
  const int lhi = lane >> 4, llo = lane & 15;
  __shared__ float wst[4][E_DIM * E_DIM];          // 16 KB, one W_p per wave

  if (blockIdx.x < 640) {
    const int u  = blockIdx.x * 256 + threadIdx.x;
    const int b  = u & (B_NUM - 1);
    const int fp = u >> 11;                        // 0..79: (f, e16-half)
    const int f  = fp >> 1;
    const float* src = x + ((size_t)b * F_NUM + f) * E_DIM + (fp & 1) * 16;
    const float4 v0 = *reinterpret_cast<const float4*>(src);
    const float4 v1 = *reinterpret_cast<const float4*>(src + 4);
    const float4 v2 = *reinterpret_cast<const float4*>(src + 8);
    const float4 v3 = *reinterpret_cast<const float4*>(src + 12);
    const int plane = f * 4 + (fp & 1) * 2;        // e8 plane index
    bf16x8 o0, o1;
    o0[0] = f2bs(v0.x); o0[1] = f2bs(v0.y); o0[2] = f2bs(v0.z); o0[3] = f2bs(v0.w);
    o0[4] = f2bs(v1.x); o0[5] = f2bs(v1.y); o0[6] = f2bs(v1.z); o0[7] = f2bs(v1.w);
    o1[0] = f2bs(v2.x); o1[1] = f2bs(v2.y); o1[2] = f2bs(v2.z); o1[3] = f2bs(v2.w);
    o1[4] = f2bs(v3.x); o1[5] = f2bs(v3.y); o1[6] = f2bs(v3.z); o1[7] = f2bs(v3.w);
    *reinterpret_cast<bf16x8*>(xbp + ((size_t)plane * B_NUM + b) * 8)       = o0;
    *reinterpret_cast<bf16x8*>(xbp + ((size_t)(plane + 1) * B_NUM + b) * 8) = o1;
  } else if (blockIdx.x < 640 + 195) {
    const int p = (blockIdx.x - 640) * 4 + wv;
    const float* Wp = W + (size_t)p * (E_DIM * E_DIM);
#pragma unroll
    for (int k = 0; k < 4; ++k) {
      float4 v = *reinterpret_cast<const float4*>(Wp + k * 256 + lane * 4);
      *reinterpret_cast<float4*>(&wst[wv][k * 256 + lane * 4]) = v;
    }
    // same-wave LDS RAW: compiler inserts lgkmcnt wait; no barrier needed
#pragma unroll
    for (int frag = 0; frag < 2; ++frag) {
      const int fo = (llo >> 2) * 8 + frag * 4 + (llo & 3);   // permuted f
      bf16x8 v;
#pragma unroll
      for (int t = 0; t < 8; ++t)
        v[t] = f2bs(wst[wv][(lhi * 8 + t) * E_DIM + fo]);     // A[m][k]=W[e=k][fo]
      *reinterpret_cast<bf16x8*>(wfrag + ((size_t)(p * 2 + frag) * 64 + lane) * 8) = v;
    }
  } else {
    for (int t = threadIdx.x; t < P_NUM * D_DIM; t += 256) dwbf[t] = f2b(dw[t]);
  }
}

// ---------------------------------------------------------------------------
// Fused dual-MFMA, 2-deep software pipeline.
// MFMA1: t[fo,b] = W_p^T xi ; u = bf16(t * xj) is the B-fragment of MFMA2
// whose A = dw[p,d] replicated over k: MFMA2 performs the f-reduction AND the
// dense fold, accumulating h[d,b] over PC_SZ pairs in one f32x4 per n-tile.
// Pair walk (ii[],jj[]) precomputed; stage buffers indexed k&1 under full
// unroll -> all register-resident. grid (16, 78), block 256 = 4 waves.
__global__ __launch_bounds__(256, 4) void fused_bilinear_dense_kernel(
    const short* __restrict__ xbp, const short* __restrict__ wfrag,
    const unsigned short* __restrict__ dwbf, float* __restrict__ hpart) {
  const int lane = threadIdx.x & 63;
  const int wv   = threadIdx.x >> 6;
  const int lhi = lane >> 4, llo = lane & 15;
  const int bb = blockIdx.x * 128 + wv * 32;
  const int pc = blockIdx.y;
  const int p0 = pc * PC_SZ;

  const int off0 = (lhi * B_NUM + bb + llo) * 8;   // within one f-plane
  const int off1 = off0 + 16 * 8;
#define XB8(f, o) (*reinterpret_cast<const bf16x8*>(xbp + (size_t)(f) * 65536 + (o)))
#define AFR(p, fr) (*reinterpret_cast<const bf16x8*>( \
    wfrag + ((size_t)((p) * 2 + (fr)) * 64 + lane) * 8))

  // pair walk for this chunk (combinations(range(40),2) order), fully static
  int ii[PC_SZ], jj[PC_SZ];
  {
    int i = 0;
    while ((i + 1) * (79 - (i + 1)) / 2 <= p0) ++i;
    ii[0] = i; jj[0] = i + 1 + (p0 - i * (79 - i) / 2);
  }
#pragma unroll
  for (int k = 1; k < PC_SZ; ++k) {
    int in_ = ii[k - 1], jn = jj[k - 1] + 1;
    if (jn == F_NUM) { ++in_; jn = in_ + 1; }
    ii[k] = in_; jj[k] = jn;
  }

  // 2-deep stages (slot = k&1; static under full unroll)
  bf16x8 sa0[2], sa1[2], sxj0[2], sxj1[2], sbf0[2], sbf1[2];
  unsigned short sdw[2];
#pragma unroll
  for (int k = 0; k < 2; ++k) {
    sa0[k] = AFR(p0 + k, 0);  sa1[k] = AFR(p0 + k, 1);
    sxj0[k] = XB8(jj[k], off0); sxj1[k] = XB8(jj[k], off1);
    sbf0[k] = XB8(ii[k], off0); sbf1[k] = XB8(ii[k], off1);
    sdw[k] = dwbf[(p0 + k) * D_DIM + llo];
  }

  f32x4 acc0 = {0.f, 0.f, 0.f, 0.f};
  f32x4 acc1 = {0.f, 0.f, 0.f, 0.f};
  const f32x4 z = {0.f, 0.f, 0.f, 0.f};

#pragma unroll
  for (int k = 0; k < PC_SZ; ++k) {
    const int s = k & 1;
    // consume stage s into locals (register renames)
    const bf16x8 a0 = sa0[s], a1 = sa1[s];
    const bf16x8 xj0 = sxj0[s], xj1 = sxj1[s];
    const bf16x8 bf0 = sbf0[s], bf1 = sbf1[s];
    const unsigned short dwb = sdw[s];
    // refill stage s with pair k+2 (lands while k, k+1 compute)
    if (k + 2 < PC_SZ) {
      sa0[s] = AFR(p0 + k + 2, 0);  sa1[s] = AFR(p0 + k + 2, 1);
      sxj0[s] = XB8(jj[k + 2], off0); sxj1[s] = XB8(jj[k + 2], off1);
      sbf0[s] = XB8(ii[k + 2], off0); sbf1[s] = XB8(ii[k + 2], off1);
      sdw[s] = dwbf[(p0 + k + 2) * D_DIM + llo];
    }

    const f32x4 c00 = __builtin_amdgcn_mfma_f32_16x16x32_bf16(a0, bf0, z, 0, 0, 0);
    const f32x4 c01 = __builtin_amdgcn_mfma_f32_16x16x32_bf16(a1, bf0, z, 0, 0, 0);
    const f32x4 c10 = __builtin_amdgcn_mfma_f32_16x16x32_bf16(a0, bf1, z, 0, 0, 0);
    const f32x4 c11 = __builtin_amdgcn_mfma_f32_16x16x32_bf16(a1, bf1, z, 0, 0, 0);

    bf16x8 a2;
#pragma unroll
    for (int t = 0; t < 8; ++t) a2[t] = (short)dwb;

    // u[k=lhi*8+t][b] = t * xj (bf16, native cvt) -> B-fragment of MFMA2
    bf16x8 u0, u1;
#pragma unroll
    for (int t = 0; t < 4; ++t) {
      u0[t]     = fcvt(c00[t] * b2f((unsigned short)xj0[t]));
      u0[t + 4] = fcvt(c01[t] * b2f((unsigned short)xj0[t + 4]));
      u1[t]     = fcvt(c10[t] * b2f((unsigned short)xj1[t]));
      u1[t + 4] = fcvt(c11[t] * b2f((unsigned short)xj1[t + 4]));
    }

    acc0 = __builtin_amdgcn_mfma_f32_16x16x32_bf16(a2, u0, acc0, 0, 0, 0);
    acc1 = __builtin_amdgcn_mfma_f32_16x16x32_bf16(a2, u1, acc1, 0, 0, 0);
  }
#undef XB8
#undef AFR

  // C2 layout: lane holds b=llo, d=lhi*4+r -> coalesced float4 stores
  float* hp = hpart + (size_t)pc * B_NUM * D_DIM;
  *reinterpret_cast<f32x4*>(hp + (size_t)(bb + llo) * D_DIM + lhi * 4) = acc0;
  *reinterpret_cast<f32x4*>(hp + (size_t)(bb + 16 + llo) * D_DIM + lhi * 4) = acc1;
}

// ---------------------------------------------------------------------------
// Final: sum 78 h-partials + bias, LayerNorm. grid 128, block 256;
// thread = (b, d): per-pc the block reads 1 KB contiguous; unroll-6 prefetch.
__global__ __launch_bounds__(256) void reduce_ln_kernel(
    const float* __restrict__ hpart, const float* __restrict__ bias,
    const float* __restrict__ gamma, const float* __restrict__ beta,
    float* __restrict__ out) {
  const int t = threadIdx.x;
  const int d = t & 15;
  const int b = blockIdx.x * 16 + (t >> 4);
  float acc = bias[d];
  const float* hp = hpart + (size_t)b * D_DIM + d;
#pragma unroll 6
  for (int pc = 0; pc < PC_N; ++pc)
    acc += hp[(size_t)pc * B_NUM * D_DIM];

  float sum = acc;
  sum += __shfl_xor(sum, 1); sum += __shfl_xor(sum, 2);
  sum += __shfl_xor(sum, 4); sum += __shfl_xor(sum, 8);
  const float mu = sum * (1.f / D_DIM);
  const float dev = acc - mu;
  float v = dev * dev;
  v += __shfl_xor(v, 1); v += __shfl_xor(v, 2);
  v += __shfl_xor(v, 4); v += __shfl_xor(v, 8);
  const float rs = rsqrtf(v * (1.f / D_DIM) + LN_EPS);
  out[(size_t)b * D_DIM + d] = dev * rs * gamma[d] + beta[d];
}

extern "C" void kernel_launch(void* const* d_in, const int* in_sizes, int n_in,
                              void* d_out, int out_size, void* d_ws, size_t ws_size,
                              hipStream_t stream) {
  const float* x     = (const float*)d_in[0];
  const float* W     = (const float*)d_in[1];
  const float* dw    = (const float*)d_in[2];
  const float* db    = (const float*)d_in[3];
  const float* gamma = (const float*)d_in[4];
  const float* beta  = (const float*)d_in[5];
  float* out = (float*)d_out;

  short*          wfrag = (short*)((char*)d_ws + WF_OFF);
  short*          xbp   = (short*)((char*)d_ws + XB_OFF);
  unsigned short* dwbf  = (unsigned short*)((char*)d_ws + DW_OFF);
  float*          hpart = (float*)((char*)d_ws + HP_OFF);

  prep_kernel<<<640 + 195 + 1, 256, 0, stream>>>(x, W, dw, xbp, wfrag, dwbf);

  dim3 gA(B_NUM / 128, PC_N);
  fused_bilinear_dense_kernel<<<gA, 256, 0, stream>>>(xbp, wfrag, dwbf, hpart);

  reduce_ln_kernel<<<B_NUM / 16, 256, 0, stream>>>(hpart, db, gamma, beta, out);
}